// Round 12
// baseline (178.483 us; speedup 1.0000x reference)
//
#include <hip/hip_runtime.h>
#include <math.h>

#define NN 40000
#define NE 640000
#define D 128
#define NH 4
#define NC 32
#define NEG 0.2f

typedef __attribute__((ext_vector_type(8))) short bf16x8;
typedef __attribute__((ext_vector_type(4))) float f32x4;

__device__ __forceinline__ unsigned pack_bf16(float a, float b) {
  unsigned ua = __float_as_uint(a), ub = __float_as_uint(b);
  ua = (ua + 0x7FFFu + ((ua >> 16) & 1u)) >> 16;
  ub = (ub + 0x7FFFu + ((ub >> 16) & 1u)) & 0xFFFF0000u;
  return ub | ua;
}

__device__ __forceinline__ bf16x8 to_bf16x8(float4 a, float4 b) {
  union { bf16x8 v; unsigned u[4]; } r;
  r.u[0] = pack_bf16(a.x, a.y);
  r.u[1] = pack_bf16(a.z, a.w);
  r.u[2] = pack_bf16(b.x, b.y);
  r.u[3] = pack_bf16(b.z, b.w);
  return r.v;
}

__device__ __forceinline__ float4 f4add(float4 a, float4 b) {
  return make_float4(a.x + b.x, a.y + b.y, a.z + b.z, a.w + b.w);
}

// ================= tables + zero counts8 (330 blocks x 256) =================
__global__ __launch_bounds__(256) void k_tables(
    const float* __restrict__ Wq, const float* __restrict__ Wk,
    const float* __restrict__ Wv,
    const float* __restrict__ att_i, const float* __restrict__ att_j,
    const float* __restrict__ eemb,
    float* __restrict__ ev, float* __restrict__ a_et,
    unsigned* __restrict__ Wvh, int* __restrict__ counts8) {
  __shared__ float sm[1024];
  int b = blockIdx.x, t = threadIdx.x;
  if (b == 0) {
    for (int j = t; j < 1024; j += 256) {
      int isq = (j < 512);
      int h = (j >> 7) & 3, d = j & 127;
      const float* __restrict__ Wm = isq ? Wq : Wk;
      const float* __restrict__ am = isq ? att_i : att_j;
      float s = 0.f;
#pragma unroll
      for (int c = 0; c < NC; ++c) s = fmaf(am[h * NC + c], Wm[(h * NC + c) * D + d], s);
      sm[j] = s;
    }
    __syncthreads();
    for (int j = t; j < 1024; j += 256) {
      int r = j >> 6;
      int c2 = (j & 63) * 2;
      float a = 0.f, bb = 0.f;
      if (r < 8) { a = sm[r * 128 + c2]; bb = sm[r * 128 + c2 + 1]; }
      Wvh[(128 + r) * 64 + (j & 63)] = pack_bf16(a, bb);
    }
    if (t < 32) {  // a_et[ty][h] = wk_eff[h] . eemb[ty]
      int ty = t >> 2, hh = t & 3;
      const float* wrow = sm + 512 + hh * 128;
      const float* __restrict__ emb = eemb + ty * D;
      float s = 0.f;
#pragma unroll 8
      for (int d = 0; d < D; ++d) s = fmaf(wrow[d], emb[d], s);
      a_et[t] = s;
    }
  } else if (b <= 8) {
    int ty = b - 1;
    if (t < 128) sm[t] = eemb[ty * D + t];
    __syncthreads();
    if (t < 128) {
      const float4* __restrict__ wr = (const float4*)(Wv + (size_t)t * D);
      const float4* __restrict__ er = (const float4*)sm;
      float s = 0.f;
#pragma unroll
      for (int k = 0; k < 32; ++k) {
        float4 ww = wr[k], ee = er[k];
        s = fmaf(ww.x, ee.x, s); s = fmaf(ww.y, ee.y, s);
        s = fmaf(ww.z, ee.z, s); s = fmaf(ww.w, ee.w, s);
      }
      ev[ty * D + t] = s;
    }
  } else if (b <= 16) {
    int j0 = (b - 9) * 1024;
    for (int j = j0 + t; j < j0 + 1024; j += 256)
      Wvh[j] = pack_bf16(Wv[2 * j], Wv[2 * j + 1]);
  } else {
    int i = (b - 17) * 256 + t;  // 313*256 = 80128 >= NN*8/4 = 80000
    if (i < NN * 8 / 4) ((int4*)counts8)[i] = make_int4(0, 0, 0, 0);
  }
}

// ====== interleaved: b%5==0 -> MFMA xv (625 blocks); else banked scatter
//        (2500 blocks, 1 edge/thread; bank = blockIdx&7; padded CSR stride 128,
//        8 sub-rows x 16 slots). Self-loops synthesized in gather. ======
__global__ __launch_bounds__(256) void k_sxi(
    const int* __restrict__ ei, const int* __restrict__ etype,
    int* __restrict__ counts8, unsigned* __restrict__ packed,
    const float* __restrict__ x, const int* __restrict__ node_type,
    const float* __restrict__ nemb, const unsigned* __restrict__ Wvh,
    unsigned* __restrict__ xvh, float* __restrict__ aq, float* __restrict__ ak) {
  int b = blockIdx.x, t = threadIdx.x;
  if (b % 5 != 0) {
    // ---- scatter: 1 edge/thread, banked tickets ----
    int sb = b - (b + 4) / 5;  // 0..2499
    int i = sb * 256 + t;      // 2500*256 = 640000 exactly
    int bank = b & 7;
    int src = ei[i];
    int dst = ei[NE + i];
    int et  = etype[i];
    int r = atomicAdd(&counts8[dst * 8 + bank], 1);
    if (r < 16)
      __builtin_nontemporal_store((unsigned)src | ((unsigned)et << 16),
                                  &packed[(dst << 7) + (bank << 4) + r]);
    return;
  }
  // ---- MFMA xv ----
  int bb = b / 5;  // 0..624
  int w = t >> 6, l = t & 63;
  int quad = l >> 4, col = l & 15;
  int n0w = bb * 64 + w * 16;  // 40000 = 625*64
  int node = n0w + col;
  int ntA = node_type[node];
  const float4* __restrict__ xr = (const float4*)(x + (size_t)node * D);
  const float4* __restrict__ nr = (const float4*)(nemb + (size_t)ntA * D);
  bf16x8 afr[4];
#pragma unroll
  for (int s = 0; s < 4; ++s) {
    const float4* p = xr + s * 8 + quad * 2;
    const float4* q4 = nr + s * 8 + quad * 2;
    afr[s] = to_bf16x8(f4add(p[0], q4[0]), f4add(p[1], q4[1]));
  }
  f32x4 acc[9];
#pragma unroll
  for (int ct = 0; ct < 9; ++ct) acc[ct] = (f32x4){0.f, 0.f, 0.f, 0.f};
#pragma unroll
  for (int ct = 0; ct < 9; ++ct) {
    const unsigned* __restrict__ brow = Wvh + (size_t)(ct * 16 + col) * 64;
#pragma unroll
    for (int s = 0; s < 4; ++s) {
      bf16x8 bfr = *(const bf16x8*)(brow + s * 16 + quad * 4);
      acc[ct] = __builtin_amdgcn_mfma_f32_16x16x32_bf16(afr[s], bfr, acc[ct], 0, 0, 0);
    }
  }
  int nodes[4];
#pragma unroll
  for (int r = 0; r < 4; ++r) nodes[r] = n0w + quad * 4 + r;
#pragma unroll
  for (int ct = 0; ct < 8; ++ct) {
#pragma unroll
    for (int r = 0; r < 4; ++r) {
      float val = acc[ct][r];
      float pv = __shfl_xor(val, 1);
      if (!(col & 1)) {
        xvh[nodes[r] * 64 + ct * 8 + (col >> 1)] = pack_bf16(val, pv);
      }
    }
  }
  if (col < 4) {
#pragma unroll
    for (int r = 0; r < 4; ++r) aq[nodes[r] * NH + col] = acc[8][r];
  } else if (col < 8) {
#pragma unroll
    for (int r = 0; r < 4; ++r) ak[nodes[r] * NH + (col - 4)] = acc[8][r];
  }
}

// item j of node n -> packed record (banked sub-rows); j >= p8 -> self-loop rec
__device__ __forceinline__ unsigned fetch_rec(const unsigned* __restrict__ packed,
    int n, int j, int p1, int p2, int p3, int p4, int p5, int p6, int p7, int p8) {
  if (j >= p8) return (unsigned)n;  // self-loop (EDGE_TYPE_SELF=0)
  int bk = (j >= p1) + (j >= p2) + (j >= p3) + (j >= p4) +
           (j >= p5) + (j >= p6) + (j >= p7);
  int pb = 0;
  pb = (j >= p1) ? p1 : pb;
  pb = (j >= p2) ? p2 : pb;
  pb = (j >= p3) ? p3 : pb;
  pb = (j >= p4) ? p4 : pb;
  pb = (j >= p5) ? p5 : pb;
  pb = (j >= p6) ? p6 : pb;
  pb = (j >= p7) ? p7 : pb;
  return packed[(n << 7) + (bk << 4) + (j - pb)];
}

// ---------------- gather: 8-way item split over banked padded CSR ----
__global__ __launch_bounds__(256) void k_gather(const int* __restrict__ counts8,
        const unsigned* __restrict__ packed,
        const float* __restrict__ aq, const float* __restrict__ ak,
        const float* __restrict__ a_et, const unsigned* __restrict__ xvh,
        const float* __restrict__ ev, const float* __restrict__ bias,
        float* __restrict__ out) {
  int n = (int)((blockIdx.x * blockDim.x + threadIdx.x) >> 6);
  int l = threadIdx.x & 63;
  if (n >= NN) return;
  int g = l >> 3, q = l & 7;
  int h = q >> 1;
  float aqh = aq[n * NH + h];
  const int4* __restrict__ c4 = (const int4*)(counts8 + n * 8);
  int4 ca = c4[0], cb = c4[1];
  int d0 = min(ca.x, 16), d1 = min(ca.y, 16), d2 = min(ca.z, 16), d3 = min(ca.w, 16);
  int d4 = min(cb.x, 16), d5 = min(cb.y, 16), d6 = min(cb.z, 16), d7 = min(cb.w, 16);
  int p1 = d0, p2 = p1 + d1, p3 = p2 + d2, p4 = p3 + d3;
  int p5 = p4 + d4, p6 = p5 + d5, p7 = p6 + d6, p8 = p7 + d7;
  int m = p8 + 1;  // + virtual self-loop at j = p8
  const uint4* __restrict__ xv4 = (const uint4*)xvh;  // row = 16 uint4
  float acc[16];
#pragma unroll
  for (int k = 0; k < 16; ++k) acc[k] = 0.f;
  float ps[8];
#pragma unroll
  for (int k = 0; k < 8; ++k) ps[k] = 0.f;
  int iters = (m + 7) >> 3;
  int i = g;
  bool val = (i < m);
  unsigned rec = fetch_rec(packed, n, i, p1, p2, p3, p4, p5, p6, p7, p8);
  int src = (int)(rec & 0xFFFFu), etc = (int)(rec >> 16);
  float sA = ak[src * NH + h] + a_et[etc * NH + h];
  uint4 vb0 = xv4[src * 16 + 2 * q];
  uint4 vb1 = xv4[src * 16 + 2 * q + 1];
  for (int it = 0; it < iters; ++it) {
    int i2 = i + 8;
    bool v2 = (i2 < m);
    float sAn = 0.f; int etn = 0;
    uint4 vb0n = make_uint4(0, 0, 0, 0), vb1n = make_uint4(0, 0, 0, 0);
    if (it + 1 < iters) {
      unsigned rec2 = fetch_rec(packed, n, i2, p1, p2, p3, p4, p5, p6, p7, p8);
      int s2 = (int)(rec2 & 0xFFFFu);
      etn = (int)(rec2 >> 16);
      sAn = ak[s2 * NH + h] + a_et[etn * NH + h];
      vb0n = xv4[s2 * 16 + 2 * q];
      vb1n = xv4[s2 * 16 + 2 * q + 1];
    }
    float s = aqh + sA;
    s = (s > 0.f) ? s : NEG * s;
    float p = val ? __expf(s) : 0.f;
#pragma unroll
    for (int tt = 0; tt < 8; ++tt) ps[tt] += (etc == tt) ? p : 0.f;
    float f[16];
    f[0]  = __uint_as_float(vb0.x << 16); f[1]  = __uint_as_float(vb0.x & 0xFFFF0000u);
    f[2]  = __uint_as_float(vb0.y << 16); f[3]  = __uint_as_float(vb0.y & 0xFFFF0000u);
    f[4]  = __uint_as_float(vb0.z << 16); f[5]  = __uint_as_float(vb0.z & 0xFFFF0000u);
    f[6]  = __uint_as_float(vb0.w << 16); f[7]  = __uint_as_float(vb0.w & 0xFFFF0000u);
    f[8]  = __uint_as_float(vb1.x << 16); f[9]  = __uint_as_float(vb1.x & 0xFFFF0000u);
    f[10] = __uint_as_float(vb1.y << 16); f[11] = __uint_as_float(vb1.y & 0xFFFF0000u);
    f[12] = __uint_as_float(vb1.z << 16); f[13] = __uint_as_float(vb1.z & 0xFFFF0000u);
    f[14] = __uint_as_float(vb1.w << 16); f[15] = __uint_as_float(vb1.w & 0xFFFF0000u);
#pragma unroll
    for (int k = 0; k < 16; ++k) acc[k] = fmaf(p, f[k], acc[k]);
    i = i2; val = v2; sA = sAn; etc = etn; vb0 = vb0n; vb1 = vb1n;
  }
#pragma unroll
  for (int tt = 0; tt < 8; ++tt) {
    ps[tt] += __shfl_xor(ps[tt], 8);
    ps[tt] += __shfl_xor(ps[tt], 16);
    ps[tt] += __shfl_xor(ps[tt], 32);
  }
  float dsum = ((ps[0] + ps[1]) + (ps[2] + ps[3])) + ((ps[4] + ps[5]) + (ps[6] + ps[7]));
  float psg = ps[0];
#pragma unroll
  for (int tt = 1; tt < 8; ++tt) psg = (g == tt) ? ps[tt] : psg;
  const float4* __restrict__ ep = (const float4*)(ev + g * D + 16 * q);
  float4 ea0 = ep[0], ea1 = ep[1], ea2 = ep[2], ea3 = ep[3];
  acc[0]  = fmaf(psg, ea0.x, acc[0]);
  acc[1]  = fmaf(psg, ea0.y, acc[1]);
  acc[2]  = fmaf(psg, ea0.z, acc[2]);
  acc[3]  = fmaf(psg, ea0.w, acc[3]);
  acc[4]  = fmaf(psg, ea1.x, acc[4]);
  acc[5]  = fmaf(psg, ea1.y, acc[5]);
  acc[6]  = fmaf(psg, ea1.z, acc[6]);
  acc[7]  = fmaf(psg, ea1.w, acc[7]);
  acc[8]  = fmaf(psg, ea2.x, acc[8]);
  acc[9]  = fmaf(psg, ea2.y, acc[9]);
  acc[10] = fmaf(psg, ea2.z, acc[10]);
  acc[11] = fmaf(psg, ea2.w, acc[11]);
  acc[12] = fmaf(psg, ea3.x, acc[12]);
  acc[13] = fmaf(psg, ea3.y, acc[13]);
  acc[14] = fmaf(psg, ea3.z, acc[14]);
  acc[15] = fmaf(psg, ea3.w, acc[15]);
#pragma unroll
  for (int k = 0; k < 16; ++k) {
    acc[k] += __shfl_xor(acc[k], 8);
    acc[k] += __shfl_xor(acc[k], 16);
    acc[k] += __shfl_xor(acc[k], 32);
  }
  if (g == 0) {
    float inv = 1.f / (dsum + 1e-16f);
    const float4* __restrict__ b4 = (const float4*)(bias + 16 * q);
    float4* __restrict__ op = (float4*)(out + (size_t)n * D + 16 * q);
#pragma unroll
    for (int k4 = 0; k4 < 4; ++k4) {
      float4 bb = b4[k4];
      op[k4] = make_float4(acc[4 * k4 + 0] * inv + bb.x,
                           acc[4 * k4 + 1] * inv + bb.y,
                           acc[4 * k4 + 2] * inv + bb.z,
                           acc[4 * k4 + 3] * inv + bb.w);
    }
  }
}

extern "C" void kernel_launch(void* const* d_in, const int* in_sizes, int n_in,
                              void* d_out, int out_size, void* d_ws, size_t ws_size,
                              hipStream_t stream) {
  const float* x      = (const float*)d_in[0];
  const int*   ei     = (const int*)d_in[1];
  const int*   ntype  = (const int*)d_in[2];
  const int*   etype  = (const int*)d_in[3];
  const float* Wq     = (const float*)d_in[4];
  const float* Wk     = (const float*)d_in[5];
  const float* Wv     = (const float*)d_in[6];
  const float* att_i  = (const float*)d_in[7];
  const float* att_j  = (const float*)d_in[8];
  const float* bias   = (const float*)d_in[9];
  const float* nemb   = (const float*)d_in[10];
  const float* eemb   = (const float*)d_in[11];
  float* out = (float*)d_out;

  float* ws      = (float*)d_ws;
  unsigned* xvh  = (unsigned*)ws;               // NN*64 uints (bf16 pairs)
  float* aq      = ws + (size_t)NN * 64;        // NN*4
  float* ak      = aq + NN * NH;                // NN*4
  float* ev      = ak + NN * NH;                // 1024
  float* a_et    = ev + 1024;                   // 32
  unsigned* Wvh  = (unsigned*)(a_et + 32);      // 144*64 = 9216 uints
  int* counts8   = (int*)(Wvh + 9216);          // NN*8 (16B aligned)
  unsigned* packed = (unsigned*)(counts8 + NN * 8);  // NN*128 banked padded CSR

  k_tables<<<dim3(330), dim3(256), 0, stream>>>(Wq, Wk, Wv, att_i, att_j, eemb,
                                                ev, a_et, Wvh, counts8);
  k_sxi<<<dim3(3125), dim3(256), 0, stream>>>(ei, etype, counts8, packed,
                                              x, ntype, nemb, Wvh, xvh, aq, ak);
  k_gather<<<dim3((NN + 3) / 4), dim3(256), 0, stream>>>(counts8, packed, aq, ak, a_et,
                                                         xvh, ev, bias, out);
}